// Round 6
// baseline (131.247 us; speedup 1.0000x reference)
//
#include <hip/hip_runtime.h>
#include <hip/hip_bf16.h>
#include <stdint.h>

#define BATCH 16384
#define INF   1024
#define OUTF  2048

#define BM 256
#define BN 256
#define BK 64
#define NT (INF / BK)   // 16 K-tiles

using bf16x8 = __attribute__((ext_vector_type(8))) __bf16;
using f32x4  = __attribute__((ext_vector_type(4))) float;
typedef unsigned short u16;

// round-to-nearest-even f32 -> bf16 (bit pattern)
__device__ __forceinline__ u16 f2bf(float f) {
  unsigned u = __builtin_bit_cast(unsigned, f);
  u += 0x7fffu + ((u >> 16) & 1u);
  return (u16)(u >> 16);
}

__device__ __forceinline__ void load_lds16(const void* g, void* l) {
  __builtin_amdgcn_global_load_lds(
      (const __attribute__((address_space(1))) unsigned*)g,
      (__attribute__((address_space(3))) unsigned*)l, 16, 0, 0);
}

// ---- x: fp32 [BATCH][INF] -> bf16 [BATCH][INF] + row sum-of-squares (fp32) ----
__global__ void __launch_bounds__(256) k_convert_x(const float* __restrict__ x,
                                                   u16* __restrict__ xb,
                                                   float* __restrict__ xsq) {
  const int row = blockIdx.x;
  const int t = threadIdx.x;
  const float4 v = reinterpret_cast<const float4*>(x + (size_t)row * INF)[t];
  ushort4 b4;
  b4.x = f2bf(v.x); b4.y = f2bf(v.y); b4.z = f2bf(v.z); b4.w = f2bf(v.w);
  reinterpret_cast<ushort4*>(xb + (size_t)row * INF)[t] = b4;

  float s = v.x * v.x + v.y * v.y + v.z * v.z + v.w * v.w;
  #pragma unroll
  for (int off = 32; off > 0; off >>= 1) s += __shfl_xor(s, off, 64);
  __shared__ float red[4];
  if ((t & 63) == 0) red[t >> 6] = s;
  __syncthreads();
  if (t == 0) xsq[row] = red[0] + red[1] + red[2] + red[3];
}

// ---- w: fp32 [INF][OUTF] -> bf16 w^T [OUTF][INF] + fused per-column sq-partials ----
__global__ void __launch_bounds__(256) k_convert_w(const float* __restrict__ w,
                                                   u16* __restrict__ wt,
                                                   float* __restrict__ part) {
  __shared__ float tile[64][65];
  __shared__ float psum[4][64];
  const int n0 = blockIdx.x * 64;   // along OUTF
  const int k0 = blockIdx.y * 64;   // along INF
  const int t = threadIdx.x;
  const int c = t & 63, r4 = t >> 6;
  float s = 0.f;
  #pragma unroll
  for (int i = 0; i < 16; ++i) {
    int k = r4 + i * 4;
    float v = w[(size_t)(k0 + k) * OUTF + n0 + c];   // coalesced over n
    tile[k][c] = v;
    s += v * v;
  }
  psum[r4][c] = s;
  __syncthreads();
  #pragma unroll
  for (int i = 0; i < 16; ++i) {
    int n = r4 + i * 4;
    wt[(size_t)(n0 + n) * INF + k0 + c] = f2bf(tile[c][n]);  // coalesced over k
  }
  if (r4 == 0)
    part[(size_t)blockIdx.y * OUTF + n0 + c] =
        psum[0][c] + psum[1][c] + psum[2][c] + psum[3][c];
}

__global__ void __launch_bounds__(256) k_wsq_final(const float* __restrict__ part,
                                                   float* __restrict__ wsq) {
  const int col = blockIdx.x * 256 + threadIdx.x;
  float s = 0.f;
  #pragma unroll
  for (int kb = 0; kb < 16; ++kb) s += part[(size_t)kb * OUTF + col];
  wsq[col] = s;
}

// ---- fused GEMM: out = xsq[row] + wsq[col] - 2 * (x @ w) ----
// 256x256 tile, BK=64, 8 waves (2Mx4N, 128x64 out each), 512 threads.
// A: LDS (64 KiB double-buffer, T2 swizzle, global_load_lds, staged 2 tiles ahead).
// B: DIRECT from global (L2-resident 512 KB panel, XCD-pinned via bx=bid&7),
//    reg-double-buffered one K-tile ahead (T14) -> halves LDS traffic, removes
//    the LDS+MFMA pipe serialization that capped rounds 2-5 at ~32% MfmaUtil.
// vmcnt(4) at tile head: B(t)+A(t) landed, A(t+2)'s 4 loads pending.
__global__ void __launch_bounds__(512, 2) k_gemm(const u16* __restrict__ A,
                                                 const u16* __restrict__ Bt,
                                                 const float* __restrict__ xsq,
                                                 const float* __restrict__ wsq,
                                                 float* __restrict__ out) {
  extern __shared__ __attribute__((aligned(16))) char lds_raw[];

  const int tid = threadIdx.x;
  const int wave = tid >> 6, lane = tid & 63;
  // XCD map: bx = bid&7 -> each XCD's L2 holds ONE 512 KB B-panel hot.
  const int bx = blockIdx.x & 7;           // 0..7  (N)
  const int by = blockIdx.x >> 3;          // 0..63 (M)
  const int rowBase = by * BM;
  const int colBase = bx * BN;
  const int wr = wave >> 2, wc = wave & 3; // 2 (M) x 4 (N) waves

  // ---- A staging (linear LDS dest, pre-swizzled global source) ----
  const int srow  = tid >> 3;                                          // 0..63
  const int ke    = (((tid & 7) * 16) ^ (((tid >> 3) & 7) << 4)) >> 1; // elem col
  const u16* aS = A + (size_t)(rowBase + srow) * INF + ke;
  char* ldsw = lds_raw + tid * 16;

  auto STAGE_A = [&](int parity, int t) {
    const int kk = t * BK;
    char* dst = ldsw + parity * 32768;
    #pragma unroll
    for (int i = 0; i < 4; ++i)
      load_lds16(aS + (size_t)(i * 64) * INF + kk, dst + i * 8192);
  };

  // ---- fragment addressing ----
  const int rf  = lane & 15;
  const int hi  = lane >> 4;                 // 0..3 (k-chunk of 8)
  const int swz = (rf & 7) << 4;
  const int aRd = (wr * 128 + rf) * 128;     // + m*2048 + ((ks*64+hi*16)^swz)
  // B direct-load base: lane reads Bt[col = colBase+wc*64+n*16+rf][k0+ks*32+hi*8..+7]
  const u16* bG = Bt + (size_t)(colBase + wc * 64 + rf) * INF + hi * 8;

  f32x4 acc[8][4] = {};
  bf16x8 bc[4][2];

  // prologue: B(0) -> regs, A(0) and A(1) -> LDS (A(1)'s 4 loads may stay pending)
  #pragma unroll
  for (int n = 0; n < 4; ++n)
    #pragma unroll
    for (int ks = 0; ks < 2; ++ks)
      bc[n][ks] = *reinterpret_cast<const bf16x8*>(bG + (size_t)n * 16 * INF + ks * 32);
  STAGE_A(0, 0);
  STAGE_A(1, 1);

  #pragma unroll
  for (int t = 0; t < NT; ++t) {
    if (t < NT - 1) asm volatile("s_waitcnt vmcnt(4)" ::: "memory");
    else            asm volatile("s_waitcnt vmcnt(0)" ::: "memory");
    __builtin_amdgcn_s_barrier();            // A(t) in buf[t&1] visible to all

    const char* buf = lds_raw + (t & 1) * 32768;

    // prefetch B(t+1) into registers (consumed next tile; ~1 tile of latency slack)
    bf16x8 bn[4][2];
    if (t + 1 < NT) {
      #pragma unroll
      for (int n = 0; n < 4; ++n)
        #pragma unroll
        for (int ks = 0; ks < 2; ++ks)
          bn[n][ks] = *reinterpret_cast<const bf16x8*>(
              bG + (size_t)n * 16 * INF + (t + 1) * BK + ks * 32);
    }

    #pragma unroll
    for (int mh = 0; mh < 2; ++mh) {
      bf16x8 a[4][2];
      #pragma unroll
      for (int mm = 0; mm < 4; ++mm)
        #pragma unroll
        for (int ks = 0; ks < 2; ++ks)
          a[mm][ks] = *reinterpret_cast<const bf16x8*>(
              buf + aRd + (mh * 4 + mm) * 2048 + ((ks * 64 + hi * 16) ^ swz));
      __builtin_amdgcn_s_setprio(1);
      #pragma unroll
      for (int mm = 0; mm < 4; ++mm)
        #pragma unroll
        for (int nn = 0; nn < 4; ++nn)
          #pragma unroll
          for (int ks = 0; ks < 2; ++ks)
            acc[mh * 4 + mm][nn] = __builtin_amdgcn_mfma_f32_16x16x32_bf16(
                a[mm][ks], bc[nn][ks], acc[mh * 4 + mm][nn], 0, 0, 0);
      __builtin_amdgcn_s_setprio(0);
    }

    asm volatile("s_waitcnt lgkmcnt(0)" ::: "memory");  // my A-reads of buf done
    __builtin_amdgcn_s_barrier();                        // all waves done reading
    if (t + 2 < NT) STAGE_A(t & 1, t + 2);               // overwrite freed buffer

    #pragma unroll
    for (int n = 0; n < 4; ++n)
      #pragma unroll
      for (int ks = 0; ks < 2; ++ks)
        bc[n][ks] = bn[n][ks];                           // reg rotate (renamed)
  }

  // ---- epilogue: C/D layout col = lane&15, row = (lane>>4)*4 + j ----
  const int cj = lane & 15;
  const int rg = hi * 4;
  #pragma unroll
  for (int m = 0; m < 8; ++m) {
    #pragma unroll
    for (int j = 0; j < 4; ++j) {
      const int row = rowBase + wr * 128 + m * 16 + rg + j;
      const float xs = xsq[row];
      #pragma unroll
      for (int n = 0; n < 4; ++n) {
        const int col = colBase + wc * 64 + n * 16 + cj;
        out[(size_t)row * OUTF + col] = xs + wsq[col] - 2.0f * acc[m][n][j];
      }
    }
  }
}

extern "C" void kernel_launch(void* const* d_in, const int* in_sizes, int n_in,
                              void* d_out, int out_size, void* d_ws, size_t ws_size,
                              hipStream_t stream) {
  const float* x = (const float*)d_in[0];
  const float* w = (const float*)d_in[1];
  float* out = (float*)d_out;

  char* ws = (char*)d_ws;
  u16* xb    = (u16*)(ws);                    // 16384*1024*2 = 33554432 B
  u16* wt    = (u16*)(ws + 33554432);         // 2048*1024*2  =  4194304 B
  float* xsq = (float*)(ws + 37748736);       // 16384*4      =    65536 B
  float* wsq = (float*)(ws + 37814272);       // 2048*4       =     8192 B
  float* prt = (float*)(ws + 37822464);       // 16*2048*4    =   131072 B

  (void)hipFuncSetAttribute(reinterpret_cast<const void*>(k_gemm),
                            hipFuncAttributeMaxDynamicSharedMemorySize, 65536);

  k_convert_x<<<BATCH, 256, 0, stream>>>(x, xb, xsq);
  k_convert_w<<<dim3(OUTF / 64, INF / 64), 256, 0, stream>>>(w, wt, prt);
  k_wsq_final<<<OUTF / 256, 256, 0, stream>>>(prt, wsq);
  k_gemm<<<512, 512, 65536, stream>>>(xb, wt, xsq, wsq, out);
}

// Round 7
// 102.088 us; speedup vs baseline: 1.2856x; 1.2856x over previous
//
#include <hip/hip_runtime.h>
#include <hip/hip_bf16.h>
#include <stdint.h>

#define BATCH 16384
#define INF   1024
#define OUTF  2048

#define BM 256
#define BN 256
#define BK 64
#define NT (INF / BK)   // 16 K-tiles

using bf16x8 = __attribute__((ext_vector_type(8))) __bf16;
using f32x4  = __attribute__((ext_vector_type(4))) float;
typedef unsigned short u16;

// round-to-nearest-even f32 -> bf16 (bit pattern)
__device__ __forceinline__ u16 f2bf(float f) {
  unsigned u = __builtin_bit_cast(unsigned, f);
  u += 0x7fffu + ((u >> 16) & 1u);
  return (u16)(u >> 16);
}

__device__ __forceinline__ void load_lds16(const void* g, void* l) {
  __builtin_amdgcn_global_load_lds(
      (const __attribute__((address_space(1))) unsigned*)g,
      (__attribute__((address_space(3))) unsigned*)l, 16, 0, 0);
}

// ---- x: fp32 [BATCH][INF] -> bf16 [BATCH][INF] + row sum-of-squares (fp32) ----
__global__ void __launch_bounds__(256) k_convert_x(const float* __restrict__ x,
                                                   u16* __restrict__ xb,
                                                   float* __restrict__ xsq) {
  const int row = blockIdx.x;
  const int t = threadIdx.x;
  const float4 v = reinterpret_cast<const float4*>(x + (size_t)row * INF)[t];
  ushort4 b4;
  b4.x = f2bf(v.x); b4.y = f2bf(v.y); b4.z = f2bf(v.z); b4.w = f2bf(v.w);
  reinterpret_cast<ushort4*>(xb + (size_t)row * INF)[t] = b4;

  float s = v.x * v.x + v.y * v.y + v.z * v.z + v.w * v.w;
  #pragma unroll
  for (int off = 32; off > 0; off >>= 1) s += __shfl_xor(s, off, 64);
  __shared__ float red[4];
  if ((t & 63) == 0) red[t >> 6] = s;
  __syncthreads();
  if (t == 0) xsq[row] = red[0] + red[1] + red[2] + red[3];
}

// ---- w: fp32 [INF][OUTF] -> FRAGMENT-MAJOR bf16 B + fused per-column sq-partials ----
// Bf element index: (((bx*16 + t)*4 + wc)*8 + f)*512 + l*8 + j   (f = nn*2+ks)
// holds B^T[col][k] with col = bx*256+wc*64+nn*16+(l&15), k = t*64+ks*32+(l>>4)*8+j.
// One 64x64 w-tile (this block) = exactly one (bx,t,wc) fragment set.
__global__ void __launch_bounds__(256) k_convert_w(const float* __restrict__ w,
                                                   u16* __restrict__ Bf,
                                                   float* __restrict__ part) {
  __shared__ float tile[64][65];   // [k][n]
  __shared__ float psum[4][64];
  const int n0 = blockIdx.x * 64;   // along OUTF
  const int k0 = blockIdx.y * 64;   // along INF
  const int tid = threadIdx.x;
  const int c = tid & 63, r4 = tid >> 6;
  float s = 0.f;
  #pragma unroll
  for (int i = 0; i < 16; ++i) {
    int k = r4 + i * 4;
    float v = w[(size_t)(k0 + k) * OUTF + n0 + c];   // coalesced over n
    tile[k][c] = v;
    s += v * v;
  }
  psum[r4][c] = s;
  __syncthreads();

  const int bx = blockIdx.x >> 2;          // 256-col block
  const int wc = blockIdx.x & 3;           // 64-col sub-block
  const int tt = blockIdx.y;               // K-tile
  u16* base = Bf + ((((size_t)bx * 16 + tt) * 4 + wc) * 8) * 512;
  const int l = tid & 63;
  #pragma unroll
  for (int fh = 0; fh < 2; ++fh) {
    const int f = (tid >> 6) * 2 + fh;     // 0..7
    const int nn = f >> 1, ks = f & 1;
    const int cl = nn * 16 + (l & 15);
    const int kl = ks * 32 + (l >> 4) * 8;
    u16 tmp[8];
    #pragma unroll
    for (int j = 0; j < 8; ++j) tmp[j] = f2bf(tile[kl + j][cl]);
    uint4 v;
    v.x = (unsigned)tmp[0] | ((unsigned)tmp[1] << 16);
    v.y = (unsigned)tmp[2] | ((unsigned)tmp[3] << 16);
    v.z = (unsigned)tmp[4] | ((unsigned)tmp[5] << 16);
    v.w = (unsigned)tmp[6] | ((unsigned)tmp[7] << 16);
    *reinterpret_cast<uint4*>(base + (size_t)f * 512 + (size_t)l * 8) = v;
  }
  if (r4 == 0)
    part[(size_t)blockIdx.y * OUTF + n0 + c] =
        psum[0][c] + psum[1][c] + psum[2][c] + psum[3][c];
}

__global__ void __launch_bounds__(256) k_wsq_final(const float* __restrict__ part,
                                                   float* __restrict__ wsq) {
  const int col = blockIdx.x * 256 + threadIdx.x;
  float s = 0.f;
  #pragma unroll
  for (int kb = 0; kb < 16; ++kb) s += part[(size_t)kb * OUTF + col];
  wsq[col] = s;
}

// ---- fused GEMM: out = xsq[row] + wsq[col] - 2 * (x @ w) ----
// 256x256 tile, BK=64, 8 waves (2Mx4N). A: single-buffered 32 KiB LDS (T2 swizzle,
// consumed-chunk overwrite -> only 2 barriers/tile). B: NO LDS — fragment-major
// global loads (lane-linear 1KB/frag, L2-resident XCD-pinned panel), reg-dbuf
// one tile ahead. vmcnt: ph0 = 0 (loads >=1 phase old), ph1 = counted 8
// (drains A13 stage only; 8 B-prefetches stay in flight).
__global__ void __launch_bounds__(512, 2) k_gemm(const u16* __restrict__ A,
                                                 const u16* __restrict__ Bf,
                                                 const float* __restrict__ xsq,
                                                 const float* __restrict__ wsq,
                                                 float* __restrict__ out) {
  extern __shared__ __attribute__((aligned(16))) char lds_raw[];  // A: [256][64] bf16

  const int tid = threadIdx.x;
  const int wave = tid >> 6, lane = tid & 63;
  const int bx = blockIdx.x & 7;           // XCD-pinned N strip (B panel L2-hot)
  const int by = blockIdx.x >> 3;
  const int rowBase = by * BM;
  const int colBase = bx * BN;
  const int wr = wave >> 2, wc = wave & 3; // 2 (M) x 4 (N)

  // A staging (linear LDS dest, pre-swizzled global source)
  const int srow = tid >> 3;                                          // 0..63
  const int ke   = (((tid & 7) * 16) ^ (((tid >> 3) & 7) << 4)) >> 1;
  const u16* aS = A + (size_t)(rowBase + srow) * INF + ke;
  char* ldsw = lds_raw + tid * 16;

  // A chunk i = rows 64i..64i+63 at bytes i*8192. Group g stages chunks {g, g+2}.
  auto STAGE_A = [&](int t, int g) {
    const int kk = t * BK;
    load_lds16(aS + (size_t)(g * 64) * INF + kk, ldsw + g * 8192);
    load_lds16(aS + (size_t)((g + 2) * 64) * INF + kk, ldsw + (g + 2) * 8192);
  };

  // fragment read addressing (A, swizzled)
  const int rf  = lane & 15;
  const int hi  = lane >> 4;
  const int swz = (rf & 7) << 4;
  const int aRd = (wr * 128 + rf) * 128;

  // fragment-major B base for this wave
  const u16* bBase = Bf + ((((size_t)bx * 16 + 0) * 4 + wc) * 8) * 512 + (size_t)lane * 8;
  // tile t at + t*16384 elems; frag f at + f*512 elems.

  f32x4 acc[8][4] = {};
  bf16x8 bc[8], bn[8];

  // prologue: A(0) chunks {0,2}; B(0) -> regs
  STAGE_A(0, 0);
  #pragma unroll
  for (int f = 0; f < 8; ++f)
    bc[f] = *reinterpret_cast<const bf16x8*>(bBase + f * 512);

  #pragma unroll
  for (int t = 0; t < NT; ++t) {
    // ---------- phase 0 (mh = 0) ----------
    asm volatile("s_waitcnt vmcnt(0)" ::: "memory");  // A02(t) + B(t) landed
    __builtin_amdgcn_s_barrier();
    STAGE_A(t, 1);                          // chunks {1,3} of CURRENT tile (read ph1)
    __builtin_amdgcn_sched_barrier(0);      // pin: A13 issued before B-prefetch
    if (t + 1 < NT) {                       // prefetch B(t+1) -> regs (coalesced, L2)
      const u16* bT = bBase + (size_t)(t + 1) * 16384;
      #pragma unroll
      for (int f = 0; f < 8; ++f)
        bn[f] = *reinterpret_cast<const bf16x8*>(bT + f * 512);
    }
    {
      bf16x8 a[4][2];
      #pragma unroll
      for (int mm = 0; mm < 4; ++mm)
        #pragma unroll
        for (int ks = 0; ks < 2; ++ks)
          a[mm][ks] = *reinterpret_cast<const bf16x8*>(
              lds_raw + aRd + mm * 2048 + ((ks * 64 + hi * 16) ^ swz));
      __builtin_amdgcn_s_setprio(1);
      #pragma unroll
      for (int mm = 0; mm < 4; ++mm)
        #pragma unroll
        for (int nn = 0; nn < 4; ++nn)
          #pragma unroll
          for (int ks = 0; ks < 2; ++ks)
            acc[mm][nn] = __builtin_amdgcn_mfma_f32_16x16x32_bf16(
                a[mm][ks], bc[nn * 2 + ks], acc[mm][nn], 0, 0, 0);
      __builtin_amdgcn_s_setprio(0);
    }

    // ---------- phase 1 (mh = 1) ----------
    if (t < NT - 1) asm volatile("s_waitcnt vmcnt(8)" ::: "memory"); // drain A13 only
    else            asm volatile("s_waitcnt vmcnt(0)" ::: "memory");
    __builtin_amdgcn_s_barrier();
    if (t + 1 < NT) STAGE_A(t + 1, 0);      // chunks {0,2} of next tile (read t+1 ph0)
    {
      bf16x8 a[4][2];
      #pragma unroll
      for (int mm = 0; mm < 4; ++mm)
        #pragma unroll
        for (int ks = 0; ks < 2; ++ks)
          a[mm][ks] = *reinterpret_cast<const bf16x8*>(
              lds_raw + aRd + (4 + mm) * 2048 + ((ks * 64 + hi * 16) ^ swz));
      __builtin_amdgcn_s_setprio(1);
      #pragma unroll
      for (int mm = 0; mm < 4; ++mm)
        #pragma unroll
        for (int nn = 0; nn < 4; ++nn)
          #pragma unroll
          for (int ks = 0; ks < 2; ++ks)
            acc[4 + mm][nn] = __builtin_amdgcn_mfma_f32_16x16x32_bf16(
                a[mm][ks], bc[nn * 2 + ks], acc[4 + mm][nn], 0, 0, 0);
      __builtin_amdgcn_s_setprio(0);
    }

    #pragma unroll
    for (int f = 0; f < 8; ++f) bc[f] = bn[f];  // rotate (static indices)
  }

  // ---- epilogue: C/D layout col = lane&15, row = (lane>>4)*4 + j ----
  const int cj = lane & 15;
  const int rg = hi * 4;
  #pragma unroll
  for (int m = 0; m < 8; ++m) {
    #pragma unroll
    for (int j = 0; j < 4; ++j) {
      const int row = rowBase + wr * 128 + m * 16 + rg + j;
      const float xs = xsq[row];
      #pragma unroll
      for (int n = 0; n < 4; ++n) {
        const int col = colBase + wc * 64 + n * 16 + cj;
        out[(size_t)row * OUTF + col] = xs + wsq[col] - 2.0f * acc[m][n][j];
      }
    }
  }
}

extern "C" void kernel_launch(void* const* d_in, const int* in_sizes, int n_in,
                              void* d_out, int out_size, void* d_ws, size_t ws_size,
                              hipStream_t stream) {
  const float* x = (const float*)d_in[0];
  const float* w = (const float*)d_in[1];
  float* out = (float*)d_out;

  char* ws = (char*)d_ws;
  u16* xb    = (u16*)(ws);                    // 16384*1024*2 = 33554432 B
  u16* Bf    = (u16*)(ws + 33554432);         // 2048*1024*2  =  4194304 B (fragment-major)
  float* xsq = (float*)(ws + 37748736);       // 16384*4      =    65536 B
  float* wsq = (float*)(ws + 37814272);       // 2048*4       =     8192 B
  float* prt = (float*)(ws + 37822464);       // 16*2048*4    =   131072 B

  (void)hipFuncSetAttribute(reinterpret_cast<const void*>(k_gemm),
                            hipFuncAttributeMaxDynamicSharedMemorySize, 32768);

  k_convert_x<<<BATCH, 256, 0, stream>>>(x, xb, xsq);
  k_convert_w<<<dim3(OUTF / 64, INF / 64), 256, 0, stream>>>(w, Bf, prt);
  k_wsq_final<<<OUTF / 256, 256, 0, stream>>>(prt, wsq);
  k_gemm<<<512, 512, 32768, stream>>>(xb, Bf, xsq, wsq, out);
}